// Round 5
// baseline (259.419 us; speedup 1.0000x reference)
//
#include <hip/hip_runtime.h>
#include <hip/hip_fp16.h>

#define BB 4
#define CC 3
#define HH 384
#define WW 384
#define FF 5
#define KK 25            // FF*FF
#define HW (HH*WW)
#define WP 192           // 16B pair-entries per row (global tables)
#define TOT (BB*HH*WP)   // entries per global table copy

#define TX 64            // tile width (pixels) — 32 lanes x 2 px
#define TY 8             // tile height
#define MX 10            // x margin (covers offx in [-8, +12])
#define MY 9             // y margin (covers offy in [-7, +8])
#define RH 28            // staged rows  [Y-9 .. Y+18]
#define NJP 45           // staged pair-entries per table per row
#define RS 1488          // LDS row stride B (2*45*16=1440 +48 pad -> 372w ≡ 20 mod 32)
#define BOFF 720         // table-B byte offset within a row (45*16)
#define SENT (RH*2*NJP)  // 2520 staged 16B entries
#define LDSB (RH*RS)     // 41664 B

typedef float fx2 __attribute__((ext_vector_type(2)));

__device__ __forceinline__ fx2 nt_load2(const float* p) {
    return __builtin_nontemporal_load((const fx2*)p);
}

// pack one pixel (3 fp32 channels) -> 8B: x = h(c0)|h(c1)<<16, y = h(c2)
__device__ __forceinline__ uint2 pack_px(float c0, float c1, float c2) {
    __half2 h01 = __floats2half2_rn(c0, c1);
    uint2 r;
    r.x = *(const unsigned int*)&h01;
    r.y = (unsigned int)__half_as_ushort(__float2half_rn(c2));
    return r;
}

// Dual fp16 pixel-pair tables (global): copy A entry j = pixels (2j,2j+1);
// copy B entry j = (2j+1, 2j+2 clamped). Any (x0,x0+1) pair with clamped
// x1 is ONE aligned 16B entry: j = x0>>1, copy = x0&1.
__global__ __launch_bounds__(256) void pack_kernel(
    const float* __restrict__ inp, uint4* __restrict__ tab)
{
    int t = blockIdx.x * blockDim.x + threadIdx.x;
    if (t >= TOT) return;
    int j = t % WP;
    int y = (t / WP) % HH;
    int b = t / (WP * HH);
    int p0 = 2 * j;
    int p2 = min(2 * j + 2, WW - 1);
    const float* b0 = inp + (((size_t)b * CC + 0) * HH + y) * WW;
    const float* b1 = inp + (((size_t)b * CC + 1) * HH + y) * WW;
    const float* b2 = inp + (((size_t)b * CC + 2) * HH + y) * WW;
    fx2 a0 = *(const fx2*)(b0 + p0);     // p0 even -> 8B aligned
    fx2 a1 = *(const fx2*)(b1 + p0);
    fx2 a2 = *(const fx2*)(b2 + p0);
    float c0 = b0[p2], c1 = b1[p2], c2 = b2[p2];
    uint2 q0 = pack_px(a0.x, a1.x, a2.x);
    uint2 q1 = pack_px(a0.y, a1.y, a2.y);
    uint2 q2 = pack_px(c0, c1, c2);
    tab[t]       = make_uint4(q0.x, q0.y, q1.x, q1.y);   // copy A
    tab[TOT + t] = make_uint4(q1.x, q1.y, q2.x, q2.y);   // copy B
}

// Fused kernel: stage BOTH pair tables for the tile region into LDS, then
// 2 px/thread deformable-sepconv. Each bilinear tap = 2 x ds_read_b128
// (rows y0, y1 at +RS immediate). All border clamping is absorbed by
// staging row-clamp + table-B construction — zero selects in inner loop.
// Out-of-margin offsets (|off|>~7, P~1e-12/sample) -> exact fp32 fallback
// behind a wave-uniform never-taken branch.
__global__ __launch_bounds__(256) void dsepconv_kernel(
    const uint4* __restrict__ tab,
    const float* __restrict__ inp,
    const float* __restrict__ vert,
    const float* __restrict__ horiz,
    const float* __restrict__ offx,
    const float* __restrict__ offy,
    const float* __restrict__ mask,
    float* __restrict__ out)
{
    __shared__ __align__(16) unsigned char lds_raw[LDSB];   // 41664 B

    int tx = threadIdx.x & 31;
    int ty = threadIdx.x >> 5;
    int X  = blockIdx.x * TX;
    int Y  = blockIdx.y * TY;
    int xb = X + tx * 2;                 // even
    int y  = Y + ty;
    int b  = blockIdx.z;
    int ylo = Y - MY, xlo = X - MX;      // xlo even
    int jp_base = xlo >> 1;
    int planeoff = y * WW + xb;          // 8B aligned

    // ---- stage both pair tables for rows [ylo, ylo+27] (coalesced 16B) ----
    const uint4* tA = tab + (size_t)b * (HH * WP);
    const uint4* tB = tA + TOT;
    for (int p = threadIdx.x; p < SENT; p += 256) {
        int r = p / (2 * NJP);               // magic-mul
        int c = p - r * (2 * NJP);           // 0..89; <45 -> A, else B
        int gy = min(max(ylo + r, 0), HH - 1);
        int idx = (c < NJP) ? c : c - NJP;
        int jg  = min(max(jp_base + idx, 0), WP - 1);
        const uint4* src = (c < NJP) ? tA : tB;
        uint4 q = src[gy * WP + jg];
        *(uint4*)(lds_raw + r * RS + c * 16) = q;   // B lands at +BOFF
    }
    __syncthreads();

    fx2 v2[FF], h2[FF];
#pragma unroll
    for (int f = 0; f < FF; ++f) {
        v2[f] = nt_load2(vert  + (b * FF + f) * HW + planeoff);
        h2[f] = nt_load2(horiz + (b * FF + f) * HW + planeoff);
    }

    const float* c0p = inp + ((size_t)b * CC + 0) * HW;
    const float* c1p = inp + ((size_t)b * CC + 1) * HW;
    const float* c2p = inp + ((size_t)b * CC + 2) * HW;

    float acc[2][3] = {{0.f,0.f,0.f},{0.f,0.f,0.f}};
    const float fy = (float)y;

    for (int ki = 0; ki < FF; ++ki) {
        float dy = fy + (float)(ki - 2);
        const float* ox_p = offx + (size_t)(b * KK + ki * FF) * HW + planeoff;
        const float* oy_p = offy + (size_t)(b * KK + ki * FF) * HW + planeoff;
        const float* m_p  = mask + (size_t)(b * KK + ki * FF) * HW + planeoff;
#pragma unroll
        for (int kj = 0; kj < FF; ++kj) {
            fx2 ox2 = nt_load2(ox_p + kj * HW);
            fx2 oy2 = nt_load2(oy_p + kj * HW);
            fx2 m2  = nt_load2(m_p  + kj * HW);
#pragma unroll
            for (int p = 0; p < 2; ++p) {
                float wt = v2[ki][p] * h2[kj][p] * m2[p];
                float py = oy2[p] + dy;
                float px = ox2[p] + (float)(xb + p + kj - 2);
                py = fminf(fmaxf(py, 0.f), (float)(HH - 1));
                px = fminf(fmaxf(px, 0.f), (float)(WW - 1));
                float y0f = floorf(py);
                float x0f = floorf(px);
                float wy = py - y0f;
                float wx = px - x0f;
                int y0 = (int)y0f;
                int x0 = (int)x0f;

                int y0r = y0 - ylo;
                int jpl = (x0 >> 1) - jp_base;   // valid for both parities
                bool ok = ((unsigned)y0r <= (unsigned)(RH - 2)) &
                          ((unsigned)jpl <= (unsigned)(NJP - 1));
                int yc = min(max(y0r, 0), RH - 2);
                int jc = min(max(jpl, 0), NJP - 1);
                int off = yc * RS + jc * 16 + ((x0 & 1) ? BOFF : 0);

                // unconditional: 2 x ds_read_b128 (rows y0, y0+1)
                uint4 r0 = *(const uint4*)(lds_raw + off);
                uint4 r1 = *(const uint4*)(lds_raw + off + RS);

                float2 f0 = __half22float2(*(const __half2*)&r0.x);
                float2 g0 = __half22float2(*(const __half2*)&r0.z);
                float2 f1 = __half22float2(*(const __half2*)&r1.x);
                float2 g1 = __half22float2(*(const __half2*)&r1.z);
                float a0c0 = f0.x, a0c1 = f0.y;      // (x0,   y0)
                float b0c0 = g0.x, b0c1 = g0.y;      // (x0+1, y0)
                float a1c0 = f1.x, a1c1 = f1.y;      // (x0,   y1)
                float b1c0 = g1.x, b1c1 = g1.y;      // (x0+1, y1)
                float a0c2 = __half2float(*(const __half*)&r0.y);
                float b0c2 = __half2float(*(const __half*)&r0.w);
                float a1c2 = __half2float(*(const __half*)&r1.y);
                float b1c2 = __half2float(*(const __half*)&r1.w);

                // correctness net: wave-uniform, statistically never taken
                if (__builtin_expect(!__all((int)ok), 0)) {
                    if (!ok) {
                        int x1  = min(x0 + 1, WW - 1);
                        int y1g = min(y0 + 1, HH - 1);
                        int o00 = y0 * WW + x0,  o01 = y0 * WW + x1;
                        int o10 = y1g * WW + x0, o11 = y1g * WW + x1;
                        a0c0 = c0p[o00]; a0c1 = c1p[o00]; a0c2 = c2p[o00];
                        b0c0 = c0p[o01]; b0c1 = c1p[o01]; b0c2 = c2p[o01];
                        a1c0 = c0p[o10]; a1c1 = c1p[o10]; a1c2 = c2p[o10];
                        b1c0 = c0p[o11]; b1c1 = c1p[o11]; b1c2 = c2p[o11];
                    }
                }

                // factored bilinear: x-lerp then y-lerp
                float t0, t1;
                t0 = a0c0 + wx * (b0c0 - a0c0);
                t1 = a1c0 + wx * (b1c0 - a1c0);
                acc[p][0] += wt * (t0 + wy * (t1 - t0));
                t0 = a0c1 + wx * (b0c1 - a0c1);
                t1 = a1c1 + wx * (b1c1 - a1c1);
                acc[p][1] += wt * (t0 + wy * (t1 - t0));
                t0 = a0c2 + wx * (b0c2 - a0c2);
                t1 = a1c2 + wx * (b1c2 - a1c2);
                acc[p][2] += wt * (t0 + wy * (t1 - t0));
            }
        }
    }

#pragma unroll
    for (int c = 0; c < CC; ++c) {
        fx2 o; o.x = acc[0][c]; o.y = acc[1][c];
        *(fx2*)(out + ((size_t)b * CC + c) * HW + planeoff) = o;
    }
}

extern "C" void kernel_launch(void* const* d_in, const int* in_sizes, int n_in,
                              void* d_out, int out_size, void* d_ws, size_t ws_size,
                              hipStream_t stream) {
    const float* inp   = (const float*)d_in[0];
    const float* vert  = (const float*)d_in[1];
    const float* horiz = (const float*)d_in[2];
    const float* offx  = (const float*)d_in[3];
    const float* offy  = (const float*)d_in[4];
    const float* mask  = (const float*)d_in[5];
    float* out = (float*)d_out;
    uint4* tab = (uint4*)d_ws;   // 2 x 4.72 MB dual pair tables

    {
        pack_kernel<<<(TOT + 255) / 256, 256, 0, stream>>>(inp, tab);
    }
    {
        dim3 grid(WW / TX, HH / TY, BB);   // 6 x 48 x 4
        dsepconv_kernel<<<grid, 256, 0, stream>>>(
            tab, inp, vert, horiz, offx, offy, mask, out);
    }
}

// Round 6
// 239.697 us; speedup vs baseline: 1.0823x; 1.0823x over previous
//
#include <hip/hip_runtime.h>
#include <hip/hip_fp16.h>

#define BB 4
#define CC 3
#define HH 384
#define WW 384
#define FF 5
#define KK 25            // FF*FF
#define HW (HH*WW)

#define TX 64            // tile width (pixels) — 32 lanes x 2 px
#define TY 8             // tile height
#define MX 10            // x margin: x0 in [X-10, X+75]
#define MY 9             // y margin: y0 in [Y-9, Y+18]
#define RH 28            // staged c2 rows   (y0r in [0,27])
#define RWC 86           // staged c2 cols   (x0r in [0,85])
#define C2S 178          // LDS row stride in dwords (712 B; 178*? mod 32 spreads rows)
#define C2N (RH*RWC)     // 2408 c2 quad entries
#define LDSW (RH*C2S)    // 4984 dwords = 19936 B

typedef float fx2 __attribute__((ext_vector_type(2)));

__device__ __forceinline__ fx2 nt_load2(const float* p) {
    return __builtin_nontemporal_load((const fx2*)p);
}
__device__ __forceinline__ unsigned h2bits(__half2 h) {
    return *(const unsigned int*)&h;
}

// Dense overlapping quad table: qtab[b*HW + y0*WW + x0] = 16B holding the
// FOUR bilinear corners (x0,x1,y0,y1; clamps baked) of channels c0,c1:
// dw0=(c0,c1)@(x0,y0) dw1=@(x1,y0) dw2=@(x0,y1) dw3=@(x1,y1).
// One 16B gather per tap/pixel replaces two -> halves L2 line-requests.
__global__ __launch_bounds__(256) void pack_kernel(
    const float* __restrict__ inp, uint4* __restrict__ qtab)
{
    int t = blockIdx.x * blockDim.x + threadIdx.x;
    if (t >= BB * HW) return;
    int b   = t / HW;
    int rem = t - b * HW;
    int y   = rem / WW;
    int x   = rem - y * WW;
    int x1  = min(x + 1, WW - 1);
    int yn  = min(y + 1, HH - 1);
    const float* c0p = inp + (size_t)b * CC * HW;
    const float* c1p = c0p + HW;
    int o00 = y * WW + x,  o01 = y * WW + x1;
    int o10 = yn * WW + x, o11 = yn * WW + x1;
    qtab[t] = make_uint4(
        h2bits(__floats2half2_rn(c0p[o00], c1p[o00])),
        h2bits(__floats2half2_rn(c0p[o01], c1p[o01])),
        h2bits(__floats2half2_rn(c0p[o10], c1p[o10])),
        h2bits(__floats2half2_rn(c0p[o11], c1p[o11])));
}

// 2 px/thread, 64x8 tile. Per tap/px: ONE 16B global gather (c0,c1 quad,
// L2-served) + ONE ds_read_b64 (c2 quad from a 20KB LDS tile). Streams
// (v,h,ox,oy,mask) are nontemporal 8B loads, bypassing L1 so it caches
// quad-table lines. c2 LDS covers |off|<=~7; escapes (P~1e-12/sample) take
// a wave-uniform exact fp32 fallback. Quad gather never needs a fallback.
__global__ __launch_bounds__(256) void dsepconv_kernel(
    const uint4* __restrict__ qtab,
    const float* __restrict__ inp,
    const float* __restrict__ vert,
    const float* __restrict__ horiz,
    const float* __restrict__ offx,
    const float* __restrict__ offy,
    const float* __restrict__ mask,
    float* __restrict__ out)
{
    __shared__ unsigned int ldsw[LDSW];   // c2 quad tile, 8B entries

    int tx = threadIdx.x & 31;
    int ty = threadIdx.x >> 5;
    int X  = blockIdx.x * TX;
    int Y  = blockIdx.y * TY;
    int xb = X + tx * 2;                 // even
    int y  = Y + ty;
    int b  = blockIdx.z;
    int ylo = Y - MY, xlo = X - MX;
    int planeoff = y * WW + xb;          // 8B aligned

    const float* c2p = inp + ((size_t)b * CC + 2) * HW;

    // ---- stage c2 quad entries: entry(r,c) = c2 at the 4 clamped corners
    // of (x0=xlo+c, y0=ylo+r). Self-contained -> entry r=RH-1 is valid.
    for (int p = threadIdx.x; p < C2N; p += 256) {
        int r = p / RWC;                 // constant div -> magic mul
        int c = p - r * RWC;
        int gy  = min(max(ylo + r, 0), HH - 1);
        int gy1 = min(gy + 1, HH - 1);
        int gx  = min(max(xlo + c, 0), WW - 1);
        int gx1 = min(gx + 1, WW - 1);
        float v00 = c2p[gy * WW + gx],  v01 = c2p[gy * WW + gx1];
        float v10 = c2p[gy1 * WW + gx], v11 = c2p[gy1 * WW + gx1];
        int o = r * C2S + c * 2;
        ldsw[o]     = h2bits(__floats2half2_rn(v00, v01));
        ldsw[o + 1] = h2bits(__floats2half2_rn(v10, v11));
    }
    __syncthreads();

    fx2 v2[FF], h2[FF];
#pragma unroll
    for (int f = 0; f < FF; ++f) {
        v2[f] = nt_load2(vert  + (b * FF + f) * HW + planeoff);
        h2[f] = nt_load2(horiz + (b * FF + f) * HW + planeoff);
    }

    const uint4* qt = qtab + (size_t)b * HW;

    float acc[2][3] = {{0.f,0.f,0.f},{0.f,0.f,0.f}};
    const float fy = (float)y;

    for (int ki = 0; ki < FF; ++ki) {
        float dy = fy + (float)(ki - 2);
        const float* ox_p = offx + (size_t)(b * KK + ki * FF) * HW + planeoff;
        const float* oy_p = offy + (size_t)(b * KK + ki * FF) * HW + planeoff;
        const float* m_p  = mask + (size_t)(b * KK + ki * FF) * HW + planeoff;
#pragma unroll
        for (int kj = 0; kj < FF; ++kj) {
            fx2 ox2 = nt_load2(ox_p + kj * HW);
            fx2 oy2 = nt_load2(oy_p + kj * HW);
            fx2 m2  = nt_load2(m_p  + kj * HW);
#pragma unroll
            for (int p = 0; p < 2; ++p) {
                float wt = v2[ki][p] * h2[kj][p] * m2[p];
                float py = oy2[p] + dy;
                float px = ox2[p] + (float)(xb + p + kj - 2);
                py = fminf(fmaxf(py, 0.f), (float)(HH - 1));
                px = fminf(fmaxf(px, 0.f), (float)(WW - 1));
                float y0f = floorf(py);
                float x0f = floorf(px);
                float wy = py - y0f;
                float wx = px - x0f;
                int y0 = (int)y0f;
                int x0 = (int)x0f;

                // c0,c1: one 16B gather, all 4 corners, clamps baked
                uint4 g = qt[y0 * WW + x0];
                float2 f00 = __half22float2(*(const __half2*)&g.x);
                float2 f01 = __half22float2(*(const __half2*)&g.y);
                float2 f10 = __half22float2(*(const __half2*)&g.z);
                float2 f11 = __half22float2(*(const __half2*)&g.w);

                // c2: one ds_read_b64 from the staged quad tile
                int y0r = y0 - ylo;
                int x0r = x0 - xlo;
                bool ok = ((unsigned)y0r <= (unsigned)(RH - 1)) &
                          ((unsigned)x0r <= (unsigned)(RWC - 1));
                int yc = min(max(y0r, 0), RH - 1);
                int xc = min(max(x0r, 0), RWC - 1);
                const unsigned int* sp = &ldsw[yc * C2S + xc * 2];
                unsigned s0 = sp[0], s1 = sp[1];
                float2 c2a = __half22float2(*(const __half2*)&s0); // @y0: x0,x1
                float2 c2b = __half22float2(*(const __half2*)&s1); // @y1: x0,x1
                float s00c2 = c2a.x, s01c2 = c2a.y;
                float s10c2 = c2b.x, s11c2 = c2b.y;

                // correctness net: wave-uniform, statistically never taken
                if (__builtin_expect(!__all((int)ok), 0)) {
                    if (!ok) {
                        int x1  = min(x0 + 1, WW - 1);
                        int y1g = min(y0 + 1, HH - 1);
                        s00c2 = c2p[y0 * WW + x0];
                        s01c2 = c2p[y0 * WW + x1];
                        s10c2 = c2p[y1g * WW + x0];
                        s11c2 = c2p[y1g * WW + x1];
                    }
                }

                float w00 = (1.f - wy) * (1.f - wx);
                float w01 = (1.f - wy) * wx;
                float w10 = wy * (1.f - wx);
                float w11 = wy * wx;

                acc[p][0] += wt * (f00.x*w00 + f01.x*w01 + f10.x*w10 + f11.x*w11);
                acc[p][1] += wt * (f00.y*w00 + f01.y*w01 + f10.y*w10 + f11.y*w11);
                acc[p][2] += wt * (s00c2*w00 + s01c2*w01 + s10c2*w10 + s11c2*w11);
            }
        }
    }

#pragma unroll
    for (int c = 0; c < CC; ++c) {
        fx2 o; o.x = acc[0][c]; o.y = acc[1][c];
        *(fx2*)(out + ((size_t)b * CC + c) * HW + planeoff) = o;
    }
}

extern "C" void kernel_launch(void* const* d_in, const int* in_sizes, int n_in,
                              void* d_out, int out_size, void* d_ws, size_t ws_size,
                              hipStream_t stream) {
    const float* inp   = (const float*)d_in[0];
    const float* vert  = (const float*)d_in[1];
    const float* horiz = (const float*)d_in[2];
    const float* offx  = (const float*)d_in[3];
    const float* offy  = (const float*)d_in[4];
    const float* mask  = (const float*)d_in[5];
    float* out = (float*)d_out;
    uint4* qtab = (uint4*)d_ws;   // 9.44 MB quad table (same as prior rounds)

    {
        pack_kernel<<<(BB * HW + 255) / 256, 256, 0, stream>>>(inp, qtab);
    }
    {
        dim3 grid(WW / TX, HH / TY, BB);   // 6 x 48 x 4
        dsepconv_kernel<<<grid, 256, 0, stream>>>(
            qtab, inp, vert, horiz, offx, offy, mask, out);
    }
}